// Round 1
// baseline (273.562 us; speedup 1.0000x reference)
//
#include <hip/hip_runtime.h>
#include <hip/hip_bf16.h>
#include <math.h>

// Problem constants (B=1)
#define T_DIM 2048
#define D_DIM 2048
#define N_HEADS 16
#define K_HEADS 8
#define H_DIM 128
#define WINDOW_SZ 1024
#define SOFT_CAP 50.0f
#define Q_SCALE 0.08838834764831845f   // 1/sqrt(128)
#define LN_BASE 9.210340371976184f     // ln(10000)

typedef __hip_bfloat16 bf16;
typedef __attribute__((ext_vector_type(8))) short short8;
typedef __attribute__((ext_vector_type(4))) float floatx4;

static __device__ __forceinline__ bf16 f2b(float v) { return __float2bfloat16(v); }
static __device__ __forceinline__ float b2f(bf16 v) { return __bfloat162float(v); }

// ---------------------------------------------------------------------------
// Fused prep: 1D grid.
//   [0, 8192)     : qkv weight transpose (32 matrices, 2048x128 -> rows z*128 of WT_qkv)
//   [8192, 12288) : out weight transpose (16 matrices, 128x2048 -> cols z*128 of WT_out)
//   [12288,14336) : x fp32 -> bf16 copy
// ---------------------------------------------------------------------------
__global__ __launch_bounds__(256) void prep_k(
    const float* __restrict__ x, const float* __restrict__ qk,
    const float* __restrict__ kvk, const float* __restrict__ ok,
    bf16* __restrict__ xb, bf16* __restrict__ WT_qkv, bf16* __restrict__ WT_out)
{
    __shared__ float tile[32][33];
    const int b = blockIdx.x;
    const int tid = threadIdx.x;
    const int tx = tid & 31, ty = tid >> 5;

    if (b < 8192) {
        const int z = b >> 8, rem = b & 255;
        const int c0 = (rem & 3) * 32;        // over H (128)
        const int r0 = (rem >> 2) * 32;       // over D (2048)
        const float* src = (z < 16) ? qk + (size_t)z * D_DIM * H_DIM
                                    : kvk + (size_t)(z - 16) * D_DIM * H_DIM;
        bf16* dst = WT_qkv + (size_t)z * 128 * 2048;
#pragma unroll
        for (int i = 0; i < 4; ++i)
            tile[ty + i * 8][tx] = src[(size_t)(r0 + ty + i * 8) * H_DIM + c0 + tx];
        __syncthreads();
#pragma unroll
        for (int i = 0; i < 4; ++i)
            dst[(size_t)(c0 + ty + i * 8) * 2048 + r0 + tx] = f2b(tile[tx][ty + i * 8]);
    } else if (b < 12288) {
        const int b2 = b - 8192;
        const int z = b2 >> 8, rem = b2 & 255;
        const int c0 = (rem & 63) * 32;       // over D (2048)
        const int r0 = (rem >> 6) * 32;       // over H (128)
        const float* src = ok + (size_t)z * H_DIM * D_DIM;
        bf16* dst = WT_out + (size_t)z * H_DIM;
#pragma unroll
        for (int i = 0; i < 4; ++i)
            tile[ty + i * 8][tx] = src[(size_t)(r0 + ty + i * 8) * D_DIM + c0 + tx];
        __syncthreads();
#pragma unroll
        for (int i = 0; i < 4; ++i)
            dst[(size_t)(c0 + ty + i * 8) * 2048 + r0 + tx] = f2b(tile[tx][ty + i * 8]);
    } else {
        const size_t i = ((size_t)(b - 12288) * 256 + tid) * 8;
        float4 a = *(const float4*)(x + i);
        float4 bb = *(const float4*)(x + i + 4);
        bf16 o[8] = {f2b(a.x), f2b(a.y), f2b(a.z), f2b(a.w),
                     f2b(bb.x), f2b(bb.y), f2b(bb.z), f2b(bb.w)};
        *(short8*)(xb + i) = *(const short8*)o;
    }
}

// ---------------------------------------------------------------------------
// 256x256 8-phase GEMM (T2+T3+T4+T5), QKV projection:
//   C[2048,4096](bf16) = A[2048x2048] * BT[4096x2048]^T
// 8 waves (2Mx4N), BK=64, 2 K-tiles/iter, double-buffered 128KiB LDS,
// counted vmcnt(6) (never 0 in loop), raw s_barrier, setprio around MFMA.
// LDS swizzle: colByte ^= (row&7)<<4, realized as inverse-permuted global
// source (linear global_load_lds dest) + swizzled ds_read addresses.
// ---------------------------------------------------------------------------
static __device__ __forceinline__ void stageT(const bf16* __restrict__ gsrc,
                                              bf16* ldst, int h, int r, int kt)
{
    __builtin_amdgcn_global_load_lds(
        (const __attribute__((address_space(1))) void*)
            (gsrc + (size_t)((h * 128 + r * 64) * 2048 + kt * 64)),
        (__attribute__((address_space(3))) void*)(ldst + h * 8192 + r * 4096),
        16, 0, 0);
}

template <int MTB>
static __device__ __forceinline__ void readA4(short8 (&dst)[4][2], const bf16* base,
                                              int rlo, const int (&cs)[2])
{
#pragma unroll
    for (int mt = 0; mt < 4; ++mt)
#pragma unroll
        for (int ks = 0; ks < 2; ++ks)
            dst[mt][ks] = *(const short8*)&base[(rlo + (MTB + mt) * 16) * 64 + cs[ks]];
}

template <int NTB>
static __device__ __forceinline__ void readB2(short8 (&dst)[2][2], const bf16* base,
                                              int rlo, const int (&cs)[2])
{
#pragma unroll
    for (int n2 = 0; n2 < 2; ++n2)
#pragma unroll
        for (int ks = 0; ks < 2; ++ks)
            dst[n2][ks] = *(const short8*)&base[(rlo + (NTB + n2) * 16) * 64 + cs[ks]];
}

template <int MB, int NB>
static __device__ __forceinline__ void mfma16(floatx4 (&acc)[8][4],
                                              const short8 (&af)[4][2],
                                              const short8 (&bf)[2][2])
{
#pragma unroll
    for (int mt = 0; mt < 4; ++mt)
#pragma unroll
        for (int n2 = 0; n2 < 2; ++n2) {
            acc[MB + mt][NB + n2] = __builtin_amdgcn_mfma_f32_16x16x32_bf16(
                af[mt][0], bf[n2][0], acc[MB + mt][NB + n2], 0, 0, 0);
            acc[MB + mt][NB + n2] = __builtin_amdgcn_mfma_f32_16x16x32_bf16(
                af[mt][1], bf[n2][1], acc[MB + mt][NB + n2], 0, 0, 0);
        }
}

__global__ __launch_bounds__(512, 2) void gemm_qkv_8ph_k(
    const bf16* __restrict__ A, const bf16* __restrict__ BT, bf16* __restrict__ C)
{
    __shared__ alignas(16) bf16 lds[2][2][16384];   // [buf][A/B][256*64]

    const int tid  = threadIdx.x;
    const int lane = tid & 63;
    const int wave = tid >> 6;
    const int lo   = lane & 15;
    const int quad = lane >> 4;

    // XCD-friendly map: wg&7 varies fastest across XCDs -> each XCD owns one
    // 256-row A panel (L2-resident) x all 16 N panels.
    const int wg   = blockIdx.x;
    const int row0 = (wg & 7) * 256;
    const int col0 = (wg >> 3) * 256;

    const int wm   = (wave >> 2) * 128;   // WARPS_M = 2
    const int wn   = (wave & 3) * 64;     // WARPS_N = 4
    const int wmlo = wm + lo, wnlo = wn + lo;

    // staging: per-thread pre-swizzled global source (lane-constant XOR)
    const int r_y   = wave * 8 + (lane >> 3);                   // 0..63
    const int c_src = ((lane & 7) ^ ((lane >> 3) & 7)) * 8;     // elements
    const bf16* pA = A  + (size_t)(row0 + r_y) * 2048 + c_src;
    const bf16* pB = BT + (size_t)(col0 + r_y) * 2048 + c_src;

    bf16* ldsA0 = &lds[0][0][0] + wave * 512;
    bf16* ldsB0 = &lds[0][1][0] + wave * 512;
    bf16* ldsA1 = &lds[1][0][0] + wave * 512;
    bf16* ldsB1 = &lds[1][1][0] + wave * 512;

    // read-side swizzled k-offsets (elements), row&7 == lo&7 for all frags
    const int cs[2] = { (quad * 8) ^ ((lo & 7) << 3),
                        (32 + quad * 8) ^ ((lo & 7) << 3) };

    floatx4 acc[8][4];
#pragma unroll
    for (int i = 0; i < 8; ++i)
#pragma unroll
        for (int j = 0; j < 4; ++j) acc[i][j] = (floatx4){0.f, 0.f, 0.f, 0.f};

    // --- prologue: A(0),B(0) -> buf0; A(1),B0(1) -> buf1 (14 loads/thread)
    stageT(pA, ldsA0, 0, 0, 0); stageT(pA, ldsA0, 0, 1, 0);
    stageT(pA, ldsA0, 1, 0, 0); stageT(pA, ldsA0, 1, 1, 0);
    stageT(pB, ldsB0, 0, 0, 0); stageT(pB, ldsB0, 0, 1, 0);
    stageT(pB, ldsB0, 1, 0, 0); stageT(pB, ldsB0, 1, 1, 0);
    stageT(pA, ldsA1, 0, 0, 1); stageT(pA, ldsA1, 0, 1, 1);
    stageT(pA, ldsA1, 1, 0, 1); stageT(pA, ldsA1, 1, 1, 1);
    stageT(pB, ldsB1, 0, 0, 1); stageT(pB, ldsB1, 0, 1, 1);
    asm volatile("s_waitcnt vmcnt(6)" ::: "memory");   // tile 0 fully landed
    __builtin_amdgcn_s_barrier();

    short8 aF[4][2], a2F[4][2], bF[2][2], b2F[2][2];

#pragma unroll 1
    for (int i = 0; i < 16; ++i) {
        const int tb1  = 2 * i + 1;
        const int tnx0 = (2 * i + 2 < 32) ? 2 * i + 2 : 31;  // clamped redundant
        const int tnx1 = (2 * i + 3 < 32) ? 2 * i + 3 : 31;  // restage at tail

        // ======== group 0: compute K-tile 2i from buf0 ========
        // p0: Q(r0,c0); stage B1(2i+1)->buf1
        readA4<0>(aF, &lds[0][0][0], wmlo, cs);
        readB2<0>(bF, &lds[0][1][0], wnlo, cs);
        stageT(pB, ldsB1, 1, 0, tb1); stageT(pB, ldsB1, 1, 1, tb1);
        __builtin_amdgcn_s_barrier();
        __builtin_amdgcn_s_setprio(1); mfma16<0, 0>(acc, aF, bF);   __builtin_amdgcn_s_setprio(0);
        __builtin_amdgcn_s_barrier();
        // p1: Q(r1,c1)
        readA4<4>(a2F, &lds[0][0][0], wmlo, cs);
        readB2<2>(b2F, &lds[0][1][0], wnlo, cs);
        __builtin_amdgcn_s_barrier();
        __builtin_amdgcn_s_setprio(1); mfma16<4, 2>(acc, a2F, b2F); __builtin_amdgcn_s_setprio(0);
        __builtin_amdgcn_s_barrier();
        // p2: Q(r0,c1); stage A(2i+2)->buf0 (buf0 A reads done at p1)
        stageT(pA, ldsA0, 0, 0, tnx0); stageT(pA, ldsA0, 0, 1, tnx0);
        stageT(pA, ldsA0, 1, 0, tnx0); stageT(pA, ldsA0, 1, 1, tnx0);
        __builtin_amdgcn_s_barrier();
        __builtin_amdgcn_s_setprio(1); mfma16<0, 2>(acc, aF, b2F);  __builtin_amdgcn_s_setprio(0);
        __builtin_amdgcn_s_barrier();
        // p3: Q(r1,c0); stage B0(2i+2)->buf0; counted vmcnt -> tile 2i+1 landed
        stageT(pB, ldsB0, 0, 0, tnx0); stageT(pB, ldsB0, 0, 1, tnx0);
        asm volatile("s_waitcnt vmcnt(6)" ::: "memory");
        __builtin_amdgcn_s_barrier();
        __builtin_amdgcn_s_setprio(1); mfma16<4, 0>(acc, a2F, bF);  __builtin_amdgcn_s_setprio(0);
        __builtin_amdgcn_s_barrier();

        // ======== group 1: compute K-tile 2i+1 from buf1 ========
        // p4: Q(r0,c0); stage B1(2i+2)->buf0
        readA4<0>(aF, &lds[1][0][0], wmlo, cs);
        readB2<0>(bF, &lds[1][1][0], wnlo, cs);
        stageT(pB, ldsB0, 1, 0, tnx0); stageT(pB, ldsB0, 1, 1, tnx0);
        __builtin_amdgcn_s_barrier();
        __builtin_amdgcn_s_setprio(1); mfma16<0, 0>(acc, aF, bF);   __builtin_amdgcn_s_setprio(0);
        __builtin_amdgcn_s_barrier();
        // p5: Q(r1,c1)
        readA4<4>(a2F, &lds[1][0][0], wmlo, cs);
        readB2<2>(b2F, &lds[1][1][0], wnlo, cs);
        __builtin_amdgcn_s_barrier();
        __builtin_amdgcn_s_setprio(1); mfma16<4, 2>(acc, a2F, b2F); __builtin_amdgcn_s_setprio(0);
        __builtin_amdgcn_s_barrier();
        // p6: Q(r0,c1); stage A(2i+3)->buf1
        stageT(pA, ldsA1, 0, 0, tnx1); stageT(pA, ldsA1, 0, 1, tnx1);
        stageT(pA, ldsA1, 1, 0, tnx1); stageT(pA, ldsA1, 1, 1, tnx1);
        __builtin_amdgcn_s_barrier();
        __builtin_amdgcn_s_setprio(1); mfma16<0, 2>(acc, aF, b2F);  __builtin_amdgcn_s_setprio(0);
        __builtin_amdgcn_s_barrier();
        // p7: Q(r1,c0); stage B0(2i+3)->buf1; counted vmcnt -> tile 2i+2 landed
        stageT(pB, ldsB1, 0, 0, tnx1); stageT(pB, ldsB1, 0, 1, tnx1);
        asm volatile("s_waitcnt vmcnt(6)" ::: "memory");
        __builtin_amdgcn_s_barrier();
        __builtin_amdgcn_s_setprio(1); mfma16<4, 0>(acc, a2F, bF);  __builtin_amdgcn_s_setprio(0);
        __builtin_amdgcn_s_barrier();
    }

    // epilogue: C write (bf16)
#pragma unroll
    for (int mt = 0; mt < 8; ++mt)
#pragma unroll
        for (int nt = 0; nt < 4; ++nt)
#pragma unroll
            for (int r = 0; r < 4; ++r) {
                int rr = row0 + wm + mt * 16 + quad * 4 + r;
                int cc = col0 + wn + nt * 16 + lo;
                C[(size_t)rr * 4096 + cc] = f2b(acc[mt][nt][r]);
            }
}

// ---------------------------------------------------------------------------
// Split-K MFMA GEMM: grid.z selects K-half; writes fp32 partials.
// 128x128 tile (m97 structure); Ndim=2048, K-half = 1024.
// ---------------------------------------------------------------------------
__global__ __launch_bounds__(256) void mfma_gemm_splitk_k(
    const bf16* __restrict__ A, const bf16* __restrict__ BT,
    float* __restrict__ P0, float* __restrict__ P1)
{
    __shared__ alignas(16) bf16 As[128 * 32];
    __shared__ alignas(16) bf16 Bs[128 * 32];

    const int tid  = threadIdx.x;
    const int lane = tid & 63;
    const int wave = tid >> 6;
    const int lo   = lane & 15;
    const int quad = lane >> 4;
    const int row0 = blockIdx.x * 128;
    const int col0 = blockIdx.y * 128;
    const int kbeg = blockIdx.z * 1024;
    float* __restrict__ P = blockIdx.z ? P1 : P0;
    const int wm = (wave >> 1) * 64;
    const int wn = (wave & 1) * 64;

    const int lrow = lane >> 2;
    const int lcol = ((lane & 3) ^ ((lane >> 3) & 3)) * 8;
    const int swk  = (quad ^ ((lo >> 1) & 3)) * 8;

    floatx4 acc[4][4];
#pragma unroll
    for (int i = 0; i < 4; ++i)
#pragma unroll
        for (int j = 0; j < 4; ++j) acc[i][j] = (floatx4){0.f, 0.f, 0.f, 0.f};

    for (int k0 = kbeg; k0 < kbeg + 1024; k0 += 32) {
        __syncthreads();
#pragma unroll
        for (int i = 0; i < 2; ++i) {
            const int trow = wave * 32 + i * 16 + lrow;
            const bf16* ga = A  + (size_t)(row0 + trow) * 2048 + k0 + lcol;
            const bf16* gb = BT + (size_t)(col0 + trow) * 2048 + k0 + lcol;
            __builtin_amdgcn_global_load_lds(
                (const __attribute__((address_space(1))) void*)ga,
                (__attribute__((address_space(3))) void*)(As + (wave * 2 + i) * 512),
                16, 0, 0);
            __builtin_amdgcn_global_load_lds(
                (const __attribute__((address_space(1))) void*)gb,
                (__attribute__((address_space(3))) void*)(Bs + (wave * 2 + i) * 512),
                16, 0, 0);
        }
        __syncthreads();

        short8 af[4], bfr[4];
#pragma unroll
        for (int mt = 0; mt < 4; ++mt)
            af[mt] = *(const short8*)&As[(wm + mt * 16 + lo) * 32 + swk];
#pragma unroll
        for (int nt = 0; nt < 4; ++nt)
            bfr[nt] = *(const short8*)&Bs[(wn + nt * 16 + lo) * 32 + swk];
#pragma unroll
        for (int mt = 0; mt < 4; ++mt)
#pragma unroll
            for (int nt = 0; nt < 4; ++nt)
                acc[mt][nt] = __builtin_amdgcn_mfma_f32_16x16x32_bf16(
                    af[mt], bfr[nt], acc[mt][nt], 0, 0, 0);
    }

#pragma unroll
    for (int mt = 0; mt < 4; ++mt)
#pragma unroll
        for (int nt = 0; nt < 4; ++nt)
#pragma unroll
            for (int r = 0; r < 4; ++r) {
                int rr = row0 + wm + mt * 16 + quad * 4 + r;
                int cc = col0 + wn + nt * 16 + lo;
                P[(size_t)rr * 2048 + cc] = acc[mt][nt][r];
            }
}

// ---------------------------------------------------------------------------
// out = P0 + P1 (float4, 4 elems/thread)
// ---------------------------------------------------------------------------
__global__ __launch_bounds__(256) void add_out_k(
    const float* __restrict__ P0, const float* __restrict__ P1,
    float* __restrict__ out)
{
    const size_t i = ((size_t)blockIdx.x * 256 + threadIdx.x) * 4;
    float4 a = *(const float4*)(P0 + i);
    float4 b = *(const float4*)(P1 + i);
    float4 o = {a.x + b.x, a.y + b.y, a.z + b.z, a.w + b.w};
    *(float4*)(out + i) = o;
}

// ---------------------------------------------------------------------------
// RoPE on K only (q-rope fused into attn). 512 pairs per t.
// ---------------------------------------------------------------------------
__global__ __launch_bounds__(256) void rope_kk(bf16* __restrict__ qkvb,
                                               const int* __restrict__ segpos)
{
    const int t = blockIdx.x;
    const float pos = (float)segpos[t];
    bf16* rowp = qkvb + (size_t)t * 4096 + 2048;
#pragma unroll
    for (int it = 0; it < 2; ++it) {
        int p = threadIdx.x + it * 256;
        int hp = p & 63;
        bf16* buf = rowp + (p >> 6) * 128;
        float fraction = (float)hp * (1.0f / 64.0f);
        float inv_ts = __expf(-fraction * LN_BASE);
        float ang = pos * inv_ts;
        float sv, cv; __sincosf(ang, &sv, &cv);
        float first  = b2f(buf[hp]);
        float second = b2f(buf[hp + 64]);
        buf[hp]      = f2b(first * cv - second * sv);
        buf[hp + 64] = f2b(second * cv + first * sv);
    }
}

// ---------------------------------------------------------------------------
// Flash MFMA attention, fixed-m softmax (softcap bounds logits to ±50).
// Q-rope fused into the Q-fragment load. (round-6 verified)
// ---------------------------------------------------------------------------
__global__ __launch_bounds__(256) void attn_k(
    const bf16* __restrict__ qkvb, const int* __restrict__ segpos,
    bf16* __restrict__ ebuf)
{
    __shared__ alignas(16) bf16 Ks[2][32][136];
    __shared__ alignas(16) bf16 Vt[2][128][40];
    __shared__ alignas(16) bf16 Ps[4][16][40];

    const int t0 = blockIdx.x * 64;
    const int n  = blockIdx.y;
    const int kh = n >> 1;
    const int tid  = threadIdx.x;
    const int lane = tid & 63;
    const int wave = tid >> 6;
    const int lo   = lane & 15;
    const int quad = lane >> 4;
    const int twlo = t0 + wave * 16;

    short8 qf[4];
    {
        const int tq = twlo + lo;
        const float pos = (float)segpos[tq];
        const bf16* qp = qkvb + (size_t)tq * 4096 + n * 128;
        float qv[4][8];
#pragma unroll
        for (int kc = 0; kc < 4; ++kc) {
            short8 raw = *(const short8*)(qp + kc * 32 + quad * 8);
            const bf16* rb = (const bf16*)&raw;
#pragma unroll
            for (int j = 0; j < 8; ++j) qv[kc][j] = b2f(rb[j]);
        }
#pragma unroll
        for (int kc = 0; kc < 2; ++kc)
#pragma unroll
            for (int j = 0; j < 8; ++j) {
                int hp = kc * 32 + quad * 8 + j;
                float ang = pos * __expf(-(float)hp * (1.0f / 64.0f) * LN_BASE);
                float sv, cv; __sincosf(ang, &sv, &cv);
                float first = qv[kc][j], second = qv[kc + 2][j];
                qv[kc][j]     = (first * cv - second * sv) * Q_SCALE;
                qv[kc + 2][j] = (second * cv + first * sv) * Q_SCALE;
            }
#pragma unroll
        for (int kc = 0; kc < 4; ++kc) {
            bf16 o[8];
#pragma unroll
            for (int j = 0; j < 8; ++j) o[j] = f2b(qv[kc][j]);
            qf[kc] = *(const short8*)o;
        }
    }

    floatx4 O[8];
#pragma unroll
    for (int i = 0; i < 8; ++i) O[i] = (floatx4){0.f, 0.f, 0.f, 0.f};
    float l_acc[4] = {0.f, 0.f, 0.f, 0.f};

    const int key_a = tid >> 3,      hd_a = (tid & 7) * 16;
    const int kp2   = (tid & 15) * 2, hd_b = (tid >> 4) * 8;

    const int s_start = (t0 > 1023) ? (t0 - 1024) : 0;
    const int nch = (t0 + 63 - s_start) / 32 + 1;

    const bf16* kg = qkvb + 2048 + kh * 128;
    const bf16* vg = qkvb + 3072 + kh * 128;

    short8 kr0 = *(const short8*)(kg + (size_t)(s_start + key_a) * 4096 + hd_a);
    short8 kr1 = *(const short8*)(kg + (size_t)(s_start + key_a) * 4096 + hd_a + 8);
    short8 vr0 = *(const short8*)(vg + (size_t)(s_start + kp2) * 4096 + hd_b);
    short8 vr1 = *(const short8*)(vg + (size_t)(s_start + kp2 + 1) * 4096 + hd_b);

    for (int c = 0; c < nch; ++c) {
        const int base = s_start + c * 32;
        const int buf = c & 1;

        *(short8*)&Ks[buf][key_a][hd_a]     = kr0;
        *(short8*)&Ks[buf][key_a][hd_a + 8] = kr1;
#pragma unroll
        for (int i = 0; i < 8; ++i) {
            unsigned pk = (unsigned)(unsigned short)vr0[i] |
                          ((unsigned)(unsigned short)vr1[i] << 16);
            *(unsigned*)&Vt[buf][hd_b + i][kp2] = pk;
        }
        if (c + 1 < nch) {
            const int nb = base + 32;
            kr0 = *(const short8*)(kg + (size_t)(nb + key_a) * 4096 + hd_a);
            kr1 = *(const short8*)(kg + (size_t)(nb + key_a) * 4096 + hd_a + 8);
            vr0 = *(const short8*)(vg + (size_t)(nb + kp2) * 4096 + hd_b);
            vr1 = *(const short8*)(vg + (size_t)(nb + kp2 + 1) * 4096 + hd_b);
        }
        __syncthreads();

        const int dbase = twlo - base;
        if (dbase >= -15 && dbase <= 1054) {
            floatx4 S0 = (floatx4){0.f, 0.f, 0.f, 0.f};
            floatx4 S1 = (floatx4){0.f, 0.f, 0.f, 0.f};
#pragma unroll
            for (int kc = 0; kc < 4; ++kc) {
                short8 b0 = *(const short8*)&Ks[buf][lo][kc * 32 + quad * 8];
                short8 b1 = *(const short8*)&Ks[buf][16 + lo][kc * 32 + quad * 8];
                S0 = __builtin_amdgcn_mfma_f32_16x16x32_bf16(qf[kc], b0, S0, 0, 0, 0);
                S1 = __builtin_amdgcn_mfma_f32_16x16x32_bf16(qf[kc], b1, S1, 0, 0, 0);
            }
            short8 vfrag[8];
#pragma unroll
            for (int nt = 0; nt < 8; ++nt)
                vfrag[nt] = *(const short8*)&Vt[buf][nt * 16 + lo][quad * 8];

            const bool need_mask = !(dbase >= 31 && dbase <= 1008);
            const int dq = dbase + quad * 4 - lo;
            float lg[2][4];
#pragma unroll
            for (int tau = 0; tau < 2; ++tau) {
#pragma unroll
                for (int r = 0; r < 4; ++r) {
                    float sv = (tau == 0) ? S0[r] : S1[r];
                    float ax = fabsf(sv) * (2.0f / SOFT_CAP);
                    float e2 = __expf(-ax);
                    float th = (1.0f - e2) * __builtin_amdgcn_rcpf(1.0f + e2);
                    float l  = copysignf(SOFT_CAP * th, sv);
                    float p  = __expf(l);
                    if (need_mask) {
                        int d = dq + r - tau * 16;
                        if ((unsigned)d > 1023u) p = 0.f;
                    }
                    lg[tau][r] = p;
                }
            }
#pragma unroll
            for (int r = 0; r < 4; ++r) l_acc[r] += lg[0][r] + lg[1][r];

#pragma unroll
            for (int tau = 0; tau < 2; ++tau)
#pragma unroll
                for (int r = 0; r < 4; ++r)
                    Ps[wave][quad * 4 + r][tau * 16 + lo] = f2b(lg[tau][r]);

            short8 pfrag = *(const short8*)&Ps[wave][lo][quad * 8];
#pragma unroll
            for (int nt = 0; nt < 8; ++nt)
                O[nt] = __builtin_amdgcn_mfma_f32_16x16x32_bf16(pfrag, vfrag[nt], O[nt], 0, 0, 0);
        }
    }

#pragma unroll
    for (int xm = 1; xm < 16; xm <<= 1)
#pragma unroll
        for (int r = 0; r < 4; ++r) l_acc[r] += __shfl_xor(l_acc[r], xm, 64);
    float invl[4];
#pragma unroll
    for (int r = 0; r < 4; ++r) invl[r] = 1.0f / l_acc[r];

#pragma unroll
    for (int nt = 0; nt < 8; ++nt)
#pragma unroll
        for (int r = 0; r < 4; ++r) {
            int t = twlo + quad * 4 + r;
            ebuf[(size_t)t * 2048 + n * 128 + nt * 16 + lo] = f2b(O[nt][r] * invl[r]);
        }
}

// ---------------------------------------------------------------------------
extern "C" void kernel_launch(void* const* d_in, const int* in_sizes, int n_in,
                              void* d_out, int out_size, void* d_ws, size_t ws_size,
                              hipStream_t stream)
{
    const float* x   = (const float*)d_in[0];
    const int*  segp = (const int*)d_in[1];
    // d_in[2] = attn_mask (bool) -- redundant with causal+window predicate, ignored
    const float* qk  = (const float*)d_in[3];
    const float* kvk = (const float*)d_in[4];
    const float* ok  = (const float*)d_in[5];

    // Workspace (48 MB): xb(0..8, aliased by ebuf) | WT_qkv(8..24) | WT_out(24..32) | qkvb(32..48)
    // After attn_k: WT_qkv and qkvb are dead -> reused as fp32 split-K partials P0/P1 (16 MB each).
    bf16* xb     = (bf16*)d_ws;
    bf16* ebuf   = xb;
    bf16* WT_qkv = xb + (size_t)4 * 1024 * 1024;
    bf16* WT_out = WT_qkv + (size_t)8 * 1024 * 1024;
    bf16* qkvb   = WT_out + (size_t)4 * 1024 * 1024;
    float* P0    = (float*)WT_qkv;
    float* P1    = (float*)qkvb;
    float* outp  = (float*)d_out;

    prep_k<<<dim3(14336), dim3(256), 0, stream>>>(x, qk, kvk, ok, xb, WT_qkv, WT_out);
    gemm_qkv_8ph_k<<<dim3(128), dim3(512), 0, stream>>>(xb, WT_qkv, qkvb);
    rope_kk<<<dim3(T_DIM), dim3(256), 0, stream>>>(qkvb, segp);
    attn_k<<<dim3(T_DIM / 64, N_HEADS), dim3(256), 0, stream>>>(qkvb, segp, ebuf);
    mfma_gemm_splitk_k<<<dim3(16, 16, 2), dim3(256), 0, stream>>>(
        ebuf, WT_out, P0, P1);
    add_out_k<<<dim3(4096), dim3(256), 0, stream>>>(P0, P1, outp);
}

// Round 2
// 259.913 us; speedup vs baseline: 1.0525x; 1.0525x over previous
//
#include <hip/hip_runtime.h>
#include <hip/hip_bf16.h>
#include <math.h>

// Problem constants (B=1)
#define T_DIM 2048
#define D_DIM 2048
#define N_HEADS 16
#define K_HEADS 8
#define H_DIM 128
#define WINDOW_SZ 1024
#define SOFT_CAP 50.0f
#define Q_SCALE 0.08838834764831845f   // 1/sqrt(128)
#define LN_BASE 9.210340371976184f     // ln(10000)

typedef __hip_bfloat16 bf16;
typedef __attribute__((ext_vector_type(8))) short short8;
typedef __attribute__((ext_vector_type(4))) float floatx4;

static __device__ __forceinline__ bf16 f2b(float v) { return __float2bfloat16(v); }
static __device__ __forceinline__ float b2f(bf16 v) { return __bfloat162float(v); }

// ---------------------------------------------------------------------------
// Fused prep: 1D grid.
//   [0, 8192)     : qkv weight transpose (32 matrices, 2048x128 -> rows z*128 of WT_qkv)
//   [8192, 12288) : out weight transpose (16 matrices, 128x2048 -> cols z*128 of WT_out)
//   [12288,14336) : x fp32 -> bf16 copy
// ---------------------------------------------------------------------------
__global__ __launch_bounds__(256) void prep_k(
    const float* __restrict__ x, const float* __restrict__ qk,
    const float* __restrict__ kvk, const float* __restrict__ ok,
    bf16* __restrict__ xb, bf16* __restrict__ WT_qkv, bf16* __restrict__ WT_out)
{
    __shared__ float tile[32][33];
    const int b = blockIdx.x;
    const int tid = threadIdx.x;
    const int tx = tid & 31, ty = tid >> 5;

    if (b < 8192) {
        const int z = b >> 8, rem = b & 255;
        const int c0 = (rem & 3) * 32;        // over H (128)
        const int r0 = (rem >> 2) * 32;       // over D (2048)
        const float* src = (z < 16) ? qk + (size_t)z * D_DIM * H_DIM
                                    : kvk + (size_t)(z - 16) * D_DIM * H_DIM;
        bf16* dst = WT_qkv + (size_t)z * 128 * 2048;
#pragma unroll
        for (int i = 0; i < 4; ++i)
            tile[ty + i * 8][tx] = src[(size_t)(r0 + ty + i * 8) * H_DIM + c0 + tx];
        __syncthreads();
#pragma unroll
        for (int i = 0; i < 4; ++i)
            dst[(size_t)(c0 + ty + i * 8) * 2048 + r0 + tx] = f2b(tile[tx][ty + i * 8]);
    } else if (b < 12288) {
        const int b2 = b - 8192;
        const int z = b2 >> 8, rem = b2 & 255;
        const int c0 = (rem & 63) * 32;       // over D (2048)
        const int r0 = (rem >> 6) * 32;       // over H (128)
        const float* src = ok + (size_t)z * H_DIM * D_DIM;
        bf16* dst = WT_out + (size_t)z * H_DIM;
#pragma unroll
        for (int i = 0; i < 4; ++i)
            tile[ty + i * 8][tx] = src[(size_t)(r0 + ty + i * 8) * D_DIM + c0 + tx];
        __syncthreads();
#pragma unroll
        for (int i = 0; i < 4; ++i)
            dst[(size_t)(c0 + ty + i * 8) * 2048 + r0 + tx] = f2b(tile[tx][ty + i * 8]);
    } else {
        const size_t i = ((size_t)(b - 12288) * 256 + tid) * 8;
        float4 a = *(const float4*)(x + i);
        float4 bb = *(const float4*)(x + i + 4);
        bf16 o[8] = {f2b(a.x), f2b(a.y), f2b(a.z), f2b(a.w),
                     f2b(bb.x), f2b(bb.y), f2b(bb.z), f2b(bb.w)};
        *(short8*)(xb + i) = *(const short8*)o;
    }
}

// ---------------------------------------------------------------------------
// 256x256 8-phase GEMM (T2+T3+T4+T5), QKV projection, SPLIT-K z=2:
//   P_z[2048,4096](bf16) = A[2048, z*1024 +: 1024] * BT[4096, same]^T
// Grid (128, 2): 256 WGs -> full 256-CU fill (round-1 fix: fill was 50%).
// z=0 -> P0 (aliases d_out as bf16 scratch), z=1 -> P1 (= qkvb);
// qkv_add_k then does qkvb += P0.
// 8 waves (2Mx4N), BK=64, 2 K-tiles/iter, double-buffered 128KiB LDS,
// counted vmcnt(6) (never 0 in loop), raw s_barrier, setprio around MFMA.
// ---------------------------------------------------------------------------
static __device__ __forceinline__ void stageT(const bf16* __restrict__ gsrc,
                                              bf16* ldst, int h, int r, int kt)
{
    __builtin_amdgcn_global_load_lds(
        (const __attribute__((address_space(1))) void*)
            (gsrc + (size_t)((h * 128 + r * 64) * 2048 + kt * 64)),
        (__attribute__((address_space(3))) void*)(ldst + h * 8192 + r * 4096),
        16, 0, 0);
}

template <int MTB>
static __device__ __forceinline__ void readA4(short8 (&dst)[4][2], const bf16* base,
                                              int rlo, const int (&cs)[2])
{
#pragma unroll
    for (int mt = 0; mt < 4; ++mt)
#pragma unroll
        for (int ks = 0; ks < 2; ++ks)
            dst[mt][ks] = *(const short8*)&base[(rlo + (MTB + mt) * 16) * 64 + cs[ks]];
}

template <int NTB>
static __device__ __forceinline__ void readB2(short8 (&dst)[2][2], const bf16* base,
                                              int rlo, const int (&cs)[2])
{
#pragma unroll
    for (int n2 = 0; n2 < 2; ++n2)
#pragma unroll
        for (int ks = 0; ks < 2; ++ks)
            dst[n2][ks] = *(const short8*)&base[(rlo + (NTB + n2) * 16) * 64 + cs[ks]];
}

template <int MB, int NB>
static __device__ __forceinline__ void mfma16(floatx4 (&acc)[8][4],
                                              const short8 (&af)[4][2],
                                              const short8 (&bf)[2][2])
{
#pragma unroll
    for (int mt = 0; mt < 4; ++mt)
#pragma unroll
        for (int n2 = 0; n2 < 2; ++n2) {
            acc[MB + mt][NB + n2] = __builtin_amdgcn_mfma_f32_16x16x32_bf16(
                af[mt][0], bf[n2][0], acc[MB + mt][NB + n2], 0, 0, 0);
            acc[MB + mt][NB + n2] = __builtin_amdgcn_mfma_f32_16x16x32_bf16(
                af[mt][1], bf[n2][1], acc[MB + mt][NB + n2], 0, 0, 0);
        }
}

__global__ __launch_bounds__(512, 2) void gemm_qkv_8ph_k(
    const bf16* __restrict__ A, const bf16* __restrict__ BT,
    bf16* __restrict__ P0, bf16* __restrict__ P1)
{
    __shared__ alignas(16) bf16 lds[2][2][16384];   // [buf][A/B][256*64]

    const int tid  = threadIdx.x;
    const int lane = tid & 63;
    const int wave = tid >> 6;
    const int lo   = lane & 15;
    const int quad = lane >> 4;

    // XCD-friendly map: wg&7 varies fastest across XCDs.
    const int wg   = blockIdx.x;
    const int row0 = (wg & 7) * 256;
    const int col0 = (wg >> 3) * 256;
    const int kb   = blockIdx.y * 16;            // K-tile base (z * 1024 elems)
    bf16* __restrict__ Pd = blockIdx.y ? P1 : P0;

    const int wm   = (wave >> 2) * 128;   // WARPS_M = 2
    const int wn   = (wave & 3) * 64;     // WARPS_N = 4
    const int wmlo = wm + lo, wnlo = wn + lo;

    // staging: per-thread pre-swizzled global source (lane-constant XOR)
    const int r_y   = wave * 8 + (lane >> 3);                   // 0..63
    const int c_src = ((lane & 7) ^ ((lane >> 3) & 7)) * 8;     // elements
    const bf16* pA = A  + (size_t)(row0 + r_y) * 2048 + c_src;
    const bf16* pB = BT + (size_t)(col0 + r_y) * 2048 + c_src;

    bf16* ldsA0 = &lds[0][0][0] + wave * 512;
    bf16* ldsB0 = &lds[0][1][0] + wave * 512;
    bf16* ldsA1 = &lds[1][0][0] + wave * 512;
    bf16* ldsB1 = &lds[1][1][0] + wave * 512;

    // read-side swizzled k-offsets (elements), row&7 == lo&7 for all frags
    const int cs[2] = { (quad * 8) ^ ((lo & 7) << 3),
                        (32 + quad * 8) ^ ((lo & 7) << 3) };

    floatx4 acc[8][4];
#pragma unroll
    for (int i = 0; i < 8; ++i)
#pragma unroll
        for (int j = 0; j < 4; ++j) acc[i][j] = (floatx4){0.f, 0.f, 0.f, 0.f};

    // --- prologue: A(kb),B(kb) -> buf0; A(kb+1),B0(kb+1) -> buf1 (14 loads)
    stageT(pA, ldsA0, 0, 0, kb); stageT(pA, ldsA0, 0, 1, kb);
    stageT(pA, ldsA0, 1, 0, kb); stageT(pA, ldsA0, 1, 1, kb);
    stageT(pB, ldsB0, 0, 0, kb); stageT(pB, ldsB0, 0, 1, kb);
    stageT(pB, ldsB0, 1, 0, kb); stageT(pB, ldsB0, 1, 1, kb);
    stageT(pA, ldsA1, 0, 0, kb + 1); stageT(pA, ldsA1, 0, 1, kb + 1);
    stageT(pA, ldsA1, 1, 0, kb + 1); stageT(pA, ldsA1, 1, 1, kb + 1);
    stageT(pB, ldsB1, 0, 0, kb + 1); stageT(pB, ldsB1, 0, 1, kb + 1);
    asm volatile("s_waitcnt vmcnt(6)" ::: "memory");   // tile kb fully landed
    __builtin_amdgcn_s_barrier();

    short8 aF[4][2], a2F[4][2], bF[2][2], b2F[2][2];

#pragma unroll 1
    for (int i = 0; i < 8; ++i) {
        const int tb1  = kb + 2 * i + 1;
        const int lt0  = (2 * i + 2 < 16) ? 2 * i + 2 : 15;  // clamped redundant
        const int lt1  = (2 * i + 3 < 16) ? 2 * i + 3 : 15;  // restage at tail
        const int tnx0 = kb + lt0;
        const int tnx1 = kb + lt1;

        // ======== group 0: compute K-tile kb+2i from buf0 ========
        // p0: Q(r0,c0); stage B1(2i+1)->buf1
        readA4<0>(aF, &lds[0][0][0], wmlo, cs);
        readB2<0>(bF, &lds[0][1][0], wnlo, cs);
        stageT(pB, ldsB1, 1, 0, tb1); stageT(pB, ldsB1, 1, 1, tb1);
        __builtin_amdgcn_s_barrier();
        __builtin_amdgcn_s_setprio(1); mfma16<0, 0>(acc, aF, bF);   __builtin_amdgcn_s_setprio(0);
        __builtin_amdgcn_s_barrier();
        // p1: Q(r1,c1)
        readA4<4>(a2F, &lds[0][0][0], wmlo, cs);
        readB2<2>(b2F, &lds[0][1][0], wnlo, cs);
        __builtin_amdgcn_s_barrier();
        __builtin_amdgcn_s_setprio(1); mfma16<4, 2>(acc, a2F, b2F); __builtin_amdgcn_s_setprio(0);
        __builtin_amdgcn_s_barrier();
        // p2: Q(r0,c1); stage A(2i+2)->buf0 (buf0 A reads done at p1)
        stageT(pA, ldsA0, 0, 0, tnx0); stageT(pA, ldsA0, 0, 1, tnx0);
        stageT(pA, ldsA0, 1, 0, tnx0); stageT(pA, ldsA0, 1, 1, tnx0);
        __builtin_amdgcn_s_barrier();
        __builtin_amdgcn_s_setprio(1); mfma16<0, 2>(acc, aF, b2F);  __builtin_amdgcn_s_setprio(0);
        __builtin_amdgcn_s_barrier();
        // p3: Q(r1,c0); stage B0(2i+2)->buf0; counted vmcnt -> tile 2i+1 landed
        stageT(pB, ldsB0, 0, 0, tnx0); stageT(pB, ldsB0, 0, 1, tnx0);
        asm volatile("s_waitcnt vmcnt(6)" ::: "memory");
        __builtin_amdgcn_s_barrier();
        __builtin_amdgcn_s_setprio(1); mfma16<4, 0>(acc, a2F, bF);  __builtin_amdgcn_s_setprio(0);
        __builtin_amdgcn_s_barrier();

        // ======== group 1: compute K-tile kb+2i+1 from buf1 ========
        // p4: Q(r0,c0); stage B1(2i+2)->buf0
        readA4<0>(aF, &lds[1][0][0], wmlo, cs);
        readB2<0>(bF, &lds[1][1][0], wnlo, cs);
        stageT(pB, ldsB0, 1, 0, tnx0); stageT(pB, ldsB0, 1, 1, tnx0);
        __builtin_amdgcn_s_barrier();
        __builtin_amdgcn_s_setprio(1); mfma16<0, 0>(acc, aF, bF);   __builtin_amdgcn_s_setprio(0);
        __builtin_amdgcn_s_barrier();
        // p5: Q(r1,c1)
        readA4<4>(a2F, &lds[1][0][0], wmlo, cs);
        readB2<2>(b2F, &lds[1][1][0], wnlo, cs);
        __builtin_amdgcn_s_barrier();
        __builtin_amdgcn_s_setprio(1); mfma16<4, 2>(acc, a2F, b2F); __builtin_amdgcn_s_setprio(0);
        __builtin_amdgcn_s_barrier();
        // p6: Q(r0,c1); stage A(2i+3)->buf1
        stageT(pA, ldsA1, 0, 0, tnx1); stageT(pA, ldsA1, 0, 1, tnx1);
        stageT(pA, ldsA1, 1, 0, tnx1); stageT(pA, ldsA1, 1, 1, tnx1);
        __builtin_amdgcn_s_barrier();
        __builtin_amdgcn_s_setprio(1); mfma16<0, 2>(acc, aF, b2F);  __builtin_amdgcn_s_setprio(0);
        __builtin_amdgcn_s_barrier();
        // p7: Q(r1,c0); stage B0(2i+3)->buf1; counted vmcnt -> tile 2i+2 landed
        stageT(pB, ldsB1, 0, 0, tnx1); stageT(pB, ldsB1, 0, 1, tnx1);
        asm volatile("s_waitcnt vmcnt(6)" ::: "memory");
        __builtin_amdgcn_s_barrier();
        __builtin_amdgcn_s_setprio(1); mfma16<4, 0>(acc, a2F, bF);  __builtin_amdgcn_s_setprio(0);
        __builtin_amdgcn_s_barrier();
    }

    // epilogue: partial write (bf16)
#pragma unroll
    for (int mt = 0; mt < 8; ++mt)
#pragma unroll
        for (int nt = 0; nt < 4; ++nt)
#pragma unroll
            for (int r = 0; r < 4; ++r) {
                int rr = row0 + wm + mt * 16 + quad * 4 + r;
                int cc = col0 + wn + nt * 16 + lo;
                Pd[(size_t)rr * 4096 + cc] = f2b(acc[mt][nt][r]);
            }
}

// ---------------------------------------------------------------------------
// qkvb += P0 (bf16 partial combine, short8-vectorized)
// ---------------------------------------------------------------------------
__global__ __launch_bounds__(256) void qkv_add_k(
    const bf16* __restrict__ P0, bf16* __restrict__ qkvb)
{
    const size_t i = ((size_t)blockIdx.x * 256 + threadIdx.x) * 8;
    short8 a = *(const short8*)(P0 + i);
    short8 b = *(const short8*)(qkvb + i);
    const bf16* ap = (const bf16*)&a;
    const bf16* bp = (const bf16*)&b;
    bf16 o[8];
#pragma unroll
    for (int j = 0; j < 8; ++j) o[j] = f2b(b2f(ap[j]) + b2f(bp[j]));
    *(short8*)(qkvb + i) = *(const short8*)o;
}

// ---------------------------------------------------------------------------
// Split-K MFMA GEMM: grid.z selects K-half; writes fp32 partials.
// 128x128 tile (m97 structure); Ndim=2048, K-half = 1024.
// ---------------------------------------------------------------------------
__global__ __launch_bounds__(256) void mfma_gemm_splitk_k(
    const bf16* __restrict__ A, const bf16* __restrict__ BT,
    float* __restrict__ P0, float* __restrict__ P1)
{
    __shared__ alignas(16) bf16 As[128 * 32];
    __shared__ alignas(16) bf16 Bs[128 * 32];

    const int tid  = threadIdx.x;
    const int lane = tid & 63;
    const int wave = tid >> 6;
    const int lo   = lane & 15;
    const int quad = lane >> 4;
    const int row0 = blockIdx.x * 128;
    const int col0 = blockIdx.y * 128;
    const int kbeg = blockIdx.z * 1024;
    float* __restrict__ P = blockIdx.z ? P1 : P0;
    const int wm = (wave >> 1) * 64;
    const int wn = (wave & 1) * 64;

    const int lrow = lane >> 2;
    const int lcol = ((lane & 3) ^ ((lane >> 3) & 3)) * 8;
    const int swk  = (quad ^ ((lo >> 1) & 3)) * 8;

    floatx4 acc[4][4];
#pragma unroll
    for (int i = 0; i < 4; ++i)
#pragma unroll
        for (int j = 0; j < 4; ++j) acc[i][j] = (floatx4){0.f, 0.f, 0.f, 0.f};

    for (int k0 = kbeg; k0 < kbeg + 1024; k0 += 32) {
        __syncthreads();
#pragma unroll
        for (int i = 0; i < 2; ++i) {
            const int trow = wave * 32 + i * 16 + lrow;
            const bf16* ga = A  + (size_t)(row0 + trow) * 2048 + k0 + lcol;
            const bf16* gb = BT + (size_t)(col0 + trow) * 2048 + k0 + lcol;
            __builtin_amdgcn_global_load_lds(
                (const __attribute__((address_space(1))) void*)ga,
                (__attribute__((address_space(3))) void*)(As + (wave * 2 + i) * 512),
                16, 0, 0);
            __builtin_amdgcn_global_load_lds(
                (const __attribute__((address_space(1))) void*)gb,
                (__attribute__((address_space(3))) void*)(Bs + (wave * 2 + i) * 512),
                16, 0, 0);
        }
        __syncthreads();

        short8 af[4], bfr[4];
#pragma unroll
        for (int mt = 0; mt < 4; ++mt)
            af[mt] = *(const short8*)&As[(wm + mt * 16 + lo) * 32 + swk];
#pragma unroll
        for (int nt = 0; nt < 4; ++nt)
            bfr[nt] = *(const short8*)&Bs[(wn + nt * 16 + lo) * 32 + swk];
#pragma unroll
        for (int mt = 0; mt < 4; ++mt)
#pragma unroll
            for (int nt = 0; nt < 4; ++nt)
                acc[mt][nt] = __builtin_amdgcn_mfma_f32_16x16x32_bf16(
                    af[mt], bfr[nt], acc[mt][nt], 0, 0, 0);
    }

#pragma unroll
    for (int mt = 0; mt < 4; ++mt)
#pragma unroll
        for (int nt = 0; nt < 4; ++nt)
#pragma unroll
            for (int r = 0; r < 4; ++r) {
                int rr = row0 + wm + mt * 16 + quad * 4 + r;
                int cc = col0 + wn + nt * 16 + lo;
                P[(size_t)rr * 2048 + cc] = acc[mt][nt][r];
            }
}

// ---------------------------------------------------------------------------
// out = P0 + P1 (float4, 4 elems/thread)
// ---------------------------------------------------------------------------
__global__ __launch_bounds__(256) void add_out_k(
    const float* __restrict__ P0, const float* __restrict__ P1,
    float* __restrict__ out)
{
    const size_t i = ((size_t)blockIdx.x * 256 + threadIdx.x) * 4;
    float4 a = *(const float4*)(P0 + i);
    float4 b = *(const float4*)(P1 + i);
    float4 o = {a.x + b.x, a.y + b.y, a.z + b.z, a.w + b.w};
    *(float4*)(out + i) = o;
}

// ---------------------------------------------------------------------------
// RoPE on K only (q-rope fused into attn). 512 pairs per t.
// ---------------------------------------------------------------------------
__global__ __launch_bounds__(256) void rope_kk(bf16* __restrict__ qkvb,
                                               const int* __restrict__ segpos)
{
    const int t = blockIdx.x;
    const float pos = (float)segpos[t];
    bf16* rowp = qkvb + (size_t)t * 4096 + 2048;
#pragma unroll
    for (int it = 0; it < 2; ++it) {
        int p = threadIdx.x + it * 256;
        int hp = p & 63;
        bf16* buf = rowp + (p >> 6) * 128;
        float fraction = (float)hp * (1.0f / 64.0f);
        float inv_ts = __expf(-fraction * LN_BASE);
        float ang = pos * inv_ts;
        float sv, cv; __sincosf(ang, &sv, &cv);
        float first  = b2f(buf[hp]);
        float second = b2f(buf[hp + 64]);
        buf[hp]      = f2b(first * cv - second * sv);
        buf[hp + 64] = f2b(second * cv + first * sv);
    }
}

// ---------------------------------------------------------------------------
// Flash MFMA attention, fixed-m softmax (softcap bounds logits to ±50).
// Q-rope fused into the Q-fragment load. (round-6 verified)
// ---------------------------------------------------------------------------
__global__ __launch_bounds__(256) void attn_k(
    const bf16* __restrict__ qkvb, const int* __restrict__ segpos,
    bf16* __restrict__ ebuf)
{
    __shared__ alignas(16) bf16 Ks[2][32][136];
    __shared__ alignas(16) bf16 Vt[2][128][40];
    __shared__ alignas(16) bf16 Ps[4][16][40];

    const int t0 = blockIdx.x * 64;
    const int n  = blockIdx.y;
    const int kh = n >> 1;
    const int tid  = threadIdx.x;
    const int lane = tid & 63;
    const int wave = tid >> 6;
    const int lo   = lane & 15;
    const int quad = lane >> 4;
    const int twlo = t0 + wave * 16;

    short8 qf[4];
    {
        const int tq = twlo + lo;
        const float pos = (float)segpos[tq];
        const bf16* qp = qkvb + (size_t)tq * 4096 + n * 128;
        float qv[4][8];
#pragma unroll
        for (int kc = 0; kc < 4; ++kc) {
            short8 raw = *(const short8*)(qp + kc * 32 + quad * 8);
            const bf16* rb = (const bf16*)&raw;
#pragma unroll
            for (int j = 0; j < 8; ++j) qv[kc][j] = b2f(rb[j]);
        }
#pragma unroll
        for (int kc = 0; kc < 2; ++kc)
#pragma unroll
            for (int j = 0; j < 8; ++j) {
                int hp = kc * 32 + quad * 8 + j;
                float ang = pos * __expf(-(float)hp * (1.0f / 64.0f) * LN_BASE);
                float sv, cv; __sincosf(ang, &sv, &cv);
                float first = qv[kc][j], second = qv[kc + 2][j];
                qv[kc][j]     = (first * cv - second * sv) * Q_SCALE;
                qv[kc + 2][j] = (second * cv + first * sv) * Q_SCALE;
            }
#pragma unroll
        for (int kc = 0; kc < 4; ++kc) {
            bf16 o[8];
#pragma unroll
            for (int j = 0; j < 8; ++j) o[j] = f2b(qv[kc][j]);
            qf[kc] = *(const short8*)o;
        }
    }

    floatx4 O[8];
#pragma unroll
    for (int i = 0; i < 8; ++i) O[i] = (floatx4){0.f, 0.f, 0.f, 0.f};
    float l_acc[4] = {0.f, 0.f, 0.f, 0.f};

    const int key_a = tid >> 3,      hd_a = (tid & 7) * 16;
    const int kp2   = (tid & 15) * 2, hd_b = (tid >> 4) * 8;

    const int s_start = (t0 > 1023) ? (t0 - 1024) : 0;
    const int nch = (t0 + 63 - s_start) / 32 + 1;

    const bf16* kg = qkvb + 2048 + kh * 128;
    const bf16* vg = qkvb + 3072 + kh * 128;

    short8 kr0 = *(const short8*)(kg + (size_t)(s_start + key_a) * 4096 + hd_a);
    short8 kr1 = *(const short8*)(kg + (size_t)(s_start + key_a) * 4096 + hd_a + 8);
    short8 vr0 = *(const short8*)(vg + (size_t)(s_start + kp2) * 4096 + hd_b);
    short8 vr1 = *(const short8*)(vg + (size_t)(s_start + kp2 + 1) * 4096 + hd_b);

    for (int c = 0; c < nch; ++c) {
        const int base = s_start + c * 32;
        const int buf = c & 1;

        *(short8*)&Ks[buf][key_a][hd_a]     = kr0;
        *(short8*)&Ks[buf][key_a][hd_a + 8] = kr1;
#pragma unroll
        for (int i = 0; i < 8; ++i) {
            unsigned pk = (unsigned)(unsigned short)vr0[i] |
                          ((unsigned)(unsigned short)vr1[i] << 16);
            *(unsigned*)&Vt[buf][hd_b + i][kp2] = pk;
        }
        if (c + 1 < nch) {
            const int nb = base + 32;
            kr0 = *(const short8*)(kg + (size_t)(nb + key_a) * 4096 + hd_a);
            kr1 = *(const short8*)(kg + (size_t)(nb + key_a) * 4096 + hd_a + 8);
            vr0 = *(const short8*)(vg + (size_t)(nb + kp2) * 4096 + hd_b);
            vr1 = *(const short8*)(vg + (size_t)(nb + kp2 + 1) * 4096 + hd_b);
        }
        __syncthreads();

        const int dbase = twlo - base;
        if (dbase >= -15 && dbase <= 1054) {
            floatx4 S0 = (floatx4){0.f, 0.f, 0.f, 0.f};
            floatx4 S1 = (floatx4){0.f, 0.f, 0.f, 0.f};
#pragma unroll
            for (int kc = 0; kc < 4; ++kc) {
                short8 b0 = *(const short8*)&Ks[buf][lo][kc * 32 + quad * 8];
                short8 b1 = *(const short8*)&Ks[buf][16 + lo][kc * 32 + quad * 8];
                S0 = __builtin_amdgcn_mfma_f32_16x16x32_bf16(qf[kc], b0, S0, 0, 0, 0);
                S1 = __builtin_amdgcn_mfma_f32_16x16x32_bf16(qf[kc], b1, S1, 0, 0, 0);
            }
            short8 vfrag[8];
#pragma unroll
            for (int nt = 0; nt < 8; ++nt)
                vfrag[nt] = *(const short8*)&Vt[buf][nt * 16 + lo][quad * 8];

            const bool need_mask = !(dbase >= 31 && dbase <= 1008);
            const int dq = dbase + quad * 4 - lo;
            float lg[2][4];
#pragma unroll
            for (int tau = 0; tau < 2; ++tau) {
#pragma unroll
                for (int r = 0; r < 4; ++r) {
                    float sv = (tau == 0) ? S0[r] : S1[r];
                    float ax = fabsf(sv) * (2.0f / SOFT_CAP);
                    float e2 = __expf(-ax);
                    float th = (1.0f - e2) * __builtin_amdgcn_rcpf(1.0f + e2);
                    float l  = copysignf(SOFT_CAP * th, sv);
                    float p  = __expf(l);
                    if (need_mask) {
                        int d = dq + r - tau * 16;
                        if ((unsigned)d > 1023u) p = 0.f;
                    }
                    lg[tau][r] = p;
                }
            }
#pragma unroll
            for (int r = 0; r < 4; ++r) l_acc[r] += lg[0][r] + lg[1][r];

#pragma unroll
            for (int tau = 0; tau < 2; ++tau)
#pragma unroll
                for (int r = 0; r < 4; ++r)
                    Ps[wave][quad * 4 + r][tau * 16 + lo] = f2b(lg[tau][r]);

            short8 pfrag = *(const short8*)&Ps[wave][lo][quad * 8];
#pragma unroll
            for (int nt = 0; nt < 8; ++nt)
                O[nt] = __builtin_amdgcn_mfma_f32_16x16x32_bf16(pfrag, vfrag[nt], O[nt], 0, 0, 0);
        }
    }

#pragma unroll
    for (int xm = 1; xm < 16; xm <<= 1)
#pragma unroll
        for (int r = 0; r < 4; ++r) l_acc[r] += __shfl_xor(l_acc[r], xm, 64);
    float invl[4];
#pragma unroll
    for (int r = 0; r < 4; ++r) invl[r] = 1.0f / l_acc[r];

#pragma unroll
    for (int nt = 0; nt < 8; ++nt)
#pragma unroll
        for (int r = 0; r < 4; ++r) {
            int t = twlo + quad * 4 + r;
            ebuf[(size_t)t * 2048 + n * 128 + nt * 16 + lo] = f2b(O[nt][r] * invl[r]);
        }
}

// ---------------------------------------------------------------------------
extern "C" void kernel_launch(void* const* d_in, const int* in_sizes, int n_in,
                              void* d_out, int out_size, void* d_ws, size_t ws_size,
                              hipStream_t stream)
{
    const float* x   = (const float*)d_in[0];
    const int*  segp = (const int*)d_in[1];
    // d_in[2] = attn_mask (bool) -- redundant with causal+window predicate, ignored
    const float* qk  = (const float*)d_in[3];
    const float* kvk = (const float*)d_in[4];
    const float* ok  = (const float*)d_in[5];

    // Workspace (~50 MB): xb(0..8, aliased by ebuf) | WT_qkv(8..24.8) | WT_out(24.8..33.2) | qkvb(33.2..50)
    // QKV split-K partial P0 aliases d_out (16.8 MB, written last by add_out_k).
    // After attn_k: WT_qkv and qkvb are dead -> reused as fp32 split-K partials for out-proj.
    bf16* xb     = (bf16*)d_ws;
    bf16* ebuf   = xb;
    bf16* WT_qkv = xb + (size_t)4 * 1024 * 1024;
    bf16* WT_out = WT_qkv + (size_t)8 * 1024 * 1024;
    bf16* qkvb   = WT_out + (size_t)4 * 1024 * 1024;
    bf16* Q0     = (bf16*)d_out;           // qkv split-K partial (z=0)
    float* P0    = (float*)WT_qkv;
    float* P1    = (float*)qkvb;
    float* outp  = (float*)d_out;

    prep_k<<<dim3(14336), dim3(256), 0, stream>>>(x, qk, kvk, ok, xb, WT_qkv, WT_out);
    gemm_qkv_8ph_k<<<dim3(128, 2), dim3(512), 0, stream>>>(xb, WT_qkv, Q0, qkvb);
    qkv_add_k<<<dim3(4096), dim3(256), 0, stream>>>(Q0, qkvb);
    rope_kk<<<dim3(T_DIM), dim3(256), 0, stream>>>(qkvb, segp);
    attn_k<<<dim3(T_DIM / 64, N_HEADS), dim3(256), 0, stream>>>(qkvb, segp, ebuf);
    mfma_gemm_splitk_k<<<dim3(16, 16, 2), dim3(256), 0, stream>>>(
        ebuf, WT_out, P0, P1);
    add_out_k<<<dim3(4096), dim3(256), 0, stream>>>(P0, P1, outp);
}